// Round 10
// baseline (210.525 us; speedup 1.0000x reference)
//
#include <hip/hip_runtime.h>
#include <hip/hip_bf16.h>

// Problem constants: B=4, F=8, C=16, H=256, W=256, K=64
#define NB 4
#define NF 8
#define NC 16
#define NK 64
#define HW 65536              // H*W
#define NBF 32                // B*F
#define BPF 64                // blocks per frame (2048 blocks)
#define PPB (HW / BPF)        // 1024 pixels per block
#define PPW (PPB / 4)         // 256 pixels per wave
#define STEPS (PPW / 32)      // 8 K-steps of 32 pixels
#define PARTSZ 1088           // per-block partial: 1024 sums + 64 counts
#define LTS 65                // uint2 stride per channel row: 64 data + 1 pad
                              // -> reads AND writes land 4 lanes/bank-pair (wave64 b64 minimum)

typedef __attribute__((ext_vector_type(8))) short bf16x8;  // MFMA A/B frag (8 bf16)
typedef __attribute__((ext_vector_type(4))) float f32x4;   // MFMA C/D frag

__device__ __forceinline__ unsigned bf16_rne(unsigned u) {
    return u + 0x7FFFu + ((u >> 16) & 1u);   // round-nearest-even (take bits >>16)
}

// r10 (= r9 intent, bug-fixed): COALESCED STAGING. r3-r8 shared one property:
// every E-load scattered 64 lanes over 16 planes 256KB apart (~16-32
// transactions/instr through the per-CU TA/L1) and time was invariant to
// occupancy/atomics/MLP. Now every global load is a contiguous 1KB wave
// transaction: 16 plane passes -> bf16 pack -> per-wave LDS strip tile
// [16 rows][65 uint2]; compute reads B-fragments straight from LDS.
// BUGFIX vs r9 draft: row stride was 33 uint2 (rows overlapped, corrupting
// the tile); now 65 = 64 data + 1 pad (also bank-conflict-minimal).
// Counts via count-MFMA (r3-verified bit-exact; MFMA pipe is idle anyway —
// an LDS histogram would serialize ~12us on the LDS-atomic pipe).
// NOTE: no min-waves launch_bounds — (256,8) caused scratch spills (r4).
__global__ __launch_bounds__(256) void accum_mfma(const float* __restrict__ E,
                                                  const int* __restrict__ T,
                                                  float* __restrict__ part) {  // [2048][PARTSZ]
    __shared__ uint2 ltile[4][NC * LTS];   // 33280 B; reused as lsum[4][64][16] in epilogue
    __shared__ int   sids[PPB];            // 4096 B
    __shared__ float lcnt[4][NK];          // 1024 B

    const int tid = threadIdx.x;
    const int wv  = tid >> 6;
    const int l   = tid & 63;
    const int col = l & 15;    // channel (B/C col) AND A row-within-tile
    const int grp = l >> 4;    // pixel-slot group

    const int bf    = blockIdx.x / BPF;
    const int chunk = blockIdx.x % BPF;
    const size_t fbase = (size_t)bf * NC * HW + (size_t)chunk * PPB;

    // ---- stage ids: block-wide coalesced int4; wave wv covers its own strip ----
    *reinterpret_cast<int4*>(&sids[tid * 4]) =
        *reinterpret_cast<const int4*>(T + (size_t)bf * HW + chunk * PPB + tid * 4);

    // ---- stage E: 16 contiguous plane passes, 2 batches of 8 (VGPR control).
    // Lane l stages strip-local pixels 4l..4l+3 of each plane.
    #pragma unroll 1
    for (int b2 = 0; b2 < 2; ++b2) {
        float4 dbuf[8];
        #pragma unroll
        for (int j = 0; j < 8; ++j)
            dbuf[j] = *reinterpret_cast<const float4*>(
                E + fbase + (size_t)(b2 * 8 + j) * HW + tid * 4);
        #pragma unroll
        for (int j = 0; j < 8; ++j) {
            union { float f[4]; unsigned u[4]; } q;
            q.f[0] = dbuf[j].x; q.f[1] = dbuf[j].y; q.f[2] = dbuf[j].z; q.f[3] = dbuf[j].w;
            uint2 pk;
            pk.x = (bf16_rne(q.u[0]) >> 16) | (bf16_rne(q.u[1]) & 0xFFFF0000u);
            pk.y = (bf16_rne(q.u[2]) >> 16) | (bf16_rne(q.u[3]) & 0xFFFF0000u);
            ltile[wv][(b2 * 8 + j) * LTS + l] = pk;
        }
    }
    // No __syncthreads: each wave reads ONLY its own strip / its own sids range;
    // wave-internal lgkmcnt ordering covers ds_write -> ds_read.

    f32x4 accS[4], accC[4];
    #pragma unroll
    for (int t = 0; t < 4; ++t) { accS[t] = (f32x4){0,0,0,0}; accC[t] = (f32x4){0,0,0,0}; }

    // Constant ones-fragment: B[p][0] = 1.0 for all p -> counts land in col 0.
    bf16x8 bOnes;
    {
        const short ov = (col == 0) ? (short)0x3F80 : (short)0;
        #pragma unroll
        for (int j = 0; j < 8; ++j) bOnes[j] = ov;
    }

    const int*   sip = &sids[wv * PPW + grp * 8];
    const uint2* bp  = &ltile[wv][col * LTS + grp * 2];

    #pragma unroll
    for (int s = 0; s < STEPS; ++s) {
        const int4 i0 = *reinterpret_cast<const int4*>(sip + s * 32);      // broadcast
        const int4 i1 = *reinterpret_cast<const int4*>(sip + s * 32 + 4);  // broadcast
        union { bf16x8 v; uint2 u2[2]; } bu;
        bu.u2[0] = bp[s * 8];              // bf16(E[ch=col][px = 8*grp + 32*s + 0..3])
        bu.u2[1] = bp[s * 8 + 1];          //                            ... + 4..7

        const int idv[8] = {i0.x, i0.y, i0.z, i0.w, i1.x, i1.y, i1.z, i1.w};
        #pragma unroll
        for (int t = 0; t < 4; ++t) {
            const int ktar = t * 16 + col;
            bf16x8 aT;
            #pragma unroll
            for (int j = 0; j < 8; ++j) aT[j] = (idv[j] == ktar) ? (short)0x3F80 : (short)0;
            accS[t] = __builtin_amdgcn_mfma_f32_16x16x32_bf16(aT, bu.v,  accS[t], 0, 0, 0);
            accC[t] = __builtin_amdgcn_mfma_f32_16x16x32_bf16(aT, bOnes, accC[t], 0, 0, 0);
        }
    }

    // ---- epilogue: cross-wave reduce (ltile memory reused), plain stores ----
    __syncthreads();   // all waves done reading ltile before overwrite
    float* lsum = reinterpret_cast<float*>(&ltile[0][0]);   // [4][64][16] = 16384 B < 33280
    #pragma unroll
    for (int t = 0; t < 4; ++t) {
        #pragma unroll
        for (int j = 0; j < 4; ++j) {
            const int k = t * 16 + grp * 4 + j;   // C/D row mapping (m89)
            lsum[((wv * NK) + k) * NC + col] = accS[t][j];
            if (col == 0) lcnt[wv][k] = accC[t][j];
        }
    }
    __syncthreads();

    float* pp = part + (size_t)blockIdx.x * PARTSZ;
    for (int i = tid; i < NK * NC; i += 256) {
        pp[i] = lsum[i] + lsum[NK*NC + i] + lsum[2*NK*NC + i] + lsum[3*NK*NC + i];
    }
    if (tid < NK) {
        pp[NK * NC + tid] = lcnt[0][tid] + lcnt[1][tid] + lcnt[2][tid] + lcnt[3][tid];
    }
}

// Sum the 64 block-partials per frame, fixed order, no atomics.
// Grid: 136 blocks x 256 threads = 34816 = 32768 sum-elems + 2048 cnt-elems.
__global__ __launch_bounds__(256) void reduce_kernel(const float* __restrict__ part,
                                                     float* __restrict__ gsum,   // [bf][k][c]
                                                     float* __restrict__ gcnt) { // [bf][k]
    const int e = blockIdx.x * 256 + threadIdx.x;
    if (e < NBF * NK * NC) {
        const int bf = e >> 10;          // / 1024
        const int i  = e & 1023;
        const float* p = part + (size_t)(bf * BPF) * PARTSZ + i;
        float s = 0.0f;
        #pragma unroll 8
        for (int blk = 0; blk < BPF; ++blk) s += p[(size_t)blk * PARTSZ];
        gsum[e] = s;
    } else {
        const int e2 = e - NBF * NK * NC;
        const int bf = e2 >> 6;
        const int k  = e2 & 63;
        const float* p = part + (size_t)(bf * BPF) * PARTSZ + NK * NC + k;
        float s = 0.0f;
        #pragma unroll 8
        for (int blk = 0; blk < BPF; ++blk) s += p[(size_t)blk * PARTSZ];
        gcnt[e2] = s;
    }
}

// Single block: 4*7*64 = 1792 (b, f-pair, k) combos, reduce to scalar.
__global__ __launch_bounds__(256) void finish_kernel(const float* __restrict__ gsum,
                                                     const float* __restrict__ gcnt,
                                                     float* __restrict__ out) {
    float total = 0.0f, nv = 0.0f;
    for (int idx = threadIdx.x; idx < NB * (NF - 1) * NK; idx += 256) {
        const int k = idx & 63;
        const int bfr = idx >> 6;
        const int b = bfr / (NF - 1);
        const int f = bfr % (NF - 1);
        const int bf0 = b * NF + f;
        if (k == 0) continue;
        const float c0 = gcnt[bf0 * NK + k];
        const float c1 = gcnt[(bf0 + 1) * NK + k];
        if (c0 > 0.0f && c1 > 0.0f) {
            const float r0 = 1.0f / c0, r1 = 1.0f / c1;
            float d = 0.0f;
            #pragma unroll
            for (int c = 0; c < NC; ++c) {
                const float m0 = gsum[(size_t)bf0 * (NK * NC) + k * NC + c] * r0;
                const float m1 = gsum[(size_t)(bf0 + 1) * (NK * NC) + k * NC + c] * r1;
                const float df = m0 - m1;
                d += df * df;
            }
            total += d;
            nv += 1.0f;
        }
    }
    const int lane = threadIdx.x & 63;
    const int wvi  = threadIdx.x >> 6;
    #pragma unroll
    for (int off = 32; off > 0; off >>= 1) {
        total += __shfl_down(total, off, 64);
        nv    += __shfl_down(nv, off, 64);
    }
    __shared__ float sT[4], sN[4];
    if (lane == 0) { sT[wvi] = total; sN[wvi] = nv; }
    __syncthreads();
    if (threadIdx.x == 0) {
        const float t = sT[0] + sT[1] + sT[2] + sT[3];
        const float n = sN[0] + sN[1] + sN[2] + sN[3];
        out[0] = (n > 0.0f) ? (t / n) : 0.0f;
    }
}

extern "C" void kernel_launch(void* const* d_in, const int* in_sizes, int n_in,
                              void* d_out, int out_size, void* d_ws, size_t ws_size,
                              hipStream_t stream) {
    const float* E = (const float*)d_in[0];   // embeddings (4,8,16,256,256) f32
    const int*   T = (const int*)d_in[1];     // track_ids  (4,8,1,256,256) i32
    float* out = (float*)d_out;

    float* part = (float*)d_ws;                          // [2048][1088] = 8.9 MB
    float* gsum = part + (size_t)(NBF * BPF) * PARTSZ;   // [32][64][16]
    float* gcnt = gsum + NBF * NK * NC;                  // [32][64]

    accum_mfma<<<NBF * BPF, 256, 0, stream>>>(E, T, part);
    reduce_kernel<<<(NBF * NK * NC + NBF * NK) / 256, 256, 0, stream>>>(part, gsum, gcnt);
    finish_kernel<<<1, 256, 0, stream>>>(gsum, gcnt, out);
}